// Round 2
// baseline (67.705 us; speedup 1.0000x reference)
//
#include <hip/hip_runtime.h>
#include <hip/hip_bf16.h>

// 3x3 median pool, stride 1, zero-pad 1, fp32 in/out.
// Input: (8, 64, 256, 256) => 512 planes of 256x256.
// Each thread computes 8 contiguous outputs along W (two float4 stores).
//
// Exact median-of-9 via column-sort factorization:
//   per column j: (lo,mi,hi) = sorted 3 vertical elems  -> v_min3/v_med3/v_max3
//   med9(k) = med3( max3(lo[k..k+2]), med3(mi[k..k+2]), min3(hi[k..k+2]) )
// Exact for the lower-median semantics (value-equal to sorted[4] of 9).

__device__ __forceinline__ float min3f(float a, float b, float c) {
    return fminf(fminf(a, b), c);
}
__device__ __forceinline__ float max3f(float a, float b, float c) {
    return fmaxf(fmaxf(a, b), c);
}
__device__ __forceinline__ float med3f(float a, float b, float c) {
    return __builtin_amdgcn_fmed3f(a, b, c);
}

__global__ __launch_bounds__(256)
void median3x3_kernel(const float* __restrict__ x, float* __restrict__ y, int total8) {
    int idx = blockIdx.x * blockDim.x + threadIdx.x;
    if (idx >= total8) return;

    // W=256 -> 32 groups of 8 per row; H=256 rows; plane index above that.
    const int w8 = idx & 31;
    const int h  = (idx >> 5) & 255;
    const int p  = idx >> 13;

    const float* plane = x + ((size_t)p << 16);   // 256*256 floats per plane
    const int c0 = w8 << 3;                        // first output column of group

    // Load 3 rows x 10 columns (c0-1 .. c0+8) with zero padding.
    float r[3][10];
#pragma unroll
    for (int dr = 0; dr < 3; ++dr) {
        const int hh = h + dr - 1;
        if (hh < 0 || hh > 255) {
#pragma unroll
            for (int j = 0; j < 10; ++j) r[dr][j] = 0.0f;
        } else {
            const float* row = plane + (hh << 8);
            const float4 a = *reinterpret_cast<const float4*>(row + c0);
            const float4 b = *reinterpret_cast<const float4*>(row + c0 + 4);
            r[dr][1] = a.x; r[dr][2] = a.y; r[dr][3] = a.z; r[dr][4] = a.w;
            r[dr][5] = b.x; r[dr][6] = b.y; r[dr][7] = b.z; r[dr][8] = b.w;
            r[dr][0] = (c0 > 0)       ? row[c0 - 1] : 0.0f;
            r[dr][9] = (c0 + 8 < 256) ? row[c0 + 8] : 0.0f;
        }
    }

    // Column-wise vertical sort: 3 instructions per column.
    float lo[10], mi[10], hi[10];
#pragma unroll
    for (int j = 0; j < 10; ++j) {
        const float a = r[0][j], b = r[1][j], c = r[2][j];
        lo[j] = min3f(a, b, c);
        mi[j] = med3f(a, b, c);
        hi[j] = max3f(a, b, c);
    }

    // Horizontal combine: 4 instructions per output.
    float res[8];
#pragma unroll
    for (int k = 0; k < 8; ++k) {
        const float A = max3f(lo[k], lo[k + 1], lo[k + 2]);
        const float B = med3f(mi[k], mi[k + 1], mi[k + 2]);
        const float C = min3f(hi[k], hi[k + 1], hi[k + 2]);
        res[k] = med3f(A, B, C);
    }

    float* out = y + ((size_t)p << 16) + (h << 8) + c0;
    *reinterpret_cast<float4*>(out)     = make_float4(res[0], res[1], res[2], res[3]);
    *reinterpret_cast<float4*>(out + 4) = make_float4(res[4], res[5], res[6], res[7]);
}

extern "C" void kernel_launch(void* const* d_in, const int* in_sizes, int n_in,
                              void* d_out, int out_size, void* d_ws, size_t ws_size,
                              hipStream_t stream) {
    const float* x = (const float*)d_in[0];
    float* y = (float*)d_out;
    const int total8 = out_size / 8;            // 4,194,304 groups of 8
    const int threads = 256;
    const int blocks = (total8 + threads - 1) / threads;
    median3x3_kernel<<<blocks, threads, 0, stream>>>(x, y, total8);
}

// Round 3
// 48.520 us; speedup vs baseline: 1.3954x; 1.3954x over previous
//
#include <hip/hip_runtime.h>
#include <hip/hip_bf16.h>

// 3x3 median pool, stride 1, zero-pad 1, fp32 in/out.
// Input: (8, 64, 256, 256) => 512 planes of 256x256.
// Each thread computes an 8-wide x 4-tall tile (32 outputs):
//   - loads 6 input rows x 10 cols once (vertical reuse: 1.5 rows/output-row
//     instead of 3), all loads issued up front for max MLP,
//   - per output row: exact median-of-9 via column-sort factorization
//     (v_min3/v_med3/v_max3), 62 ops per 8 outputs.

__device__ __forceinline__ float min3f(float a, float b, float c) {
    return fminf(fminf(a, b), c);
}
__device__ __forceinline__ float max3f(float a, float b, float c) {
    return fmaxf(fmaxf(a, b), c);
}
__device__ __forceinline__ float med3f(float a, float b, float c) {
    return __builtin_amdgcn_fmed3f(a, b, c);
}

__global__ __launch_bounds__(256)
void median3x3_kernel(const float* __restrict__ x, float* __restrict__ y, int total) {
    int idx = blockIdx.x * blockDim.x + threadIdx.x;
    if (idx >= total) return;

    // Decomposition: 32 col-groups (8 wide) x 64 row-strips (4 tall) x 512 planes.
    const int w8 = idx & 31;
    const int hs = (idx >> 5) & 63;
    const int p  = idx >> 11;

    const float* plane = x + ((size_t)p << 16);   // 256*256 floats per plane
    const int c0 = w8 << 3;                        // first output column
    const int h0 = hs << 2;                        // first output row

    // Load 6 input rows (h0-1 .. h0+4) x 10 cols (c0-1 .. c0+8), zero padded.
    float r[6][10];
#pragma unroll
    for (int t = 0; t < 6; ++t) {
        const int hh = h0 + t - 1;
        if (hh < 0 || hh > 255) {
#pragma unroll
            for (int j = 0; j < 10; ++j) r[t][j] = 0.0f;
        } else {
            const float* row = plane + (hh << 8);
            const float4 a = *reinterpret_cast<const float4*>(row + c0);
            const float4 b = *reinterpret_cast<const float4*>(row + c0 + 4);
            r[t][1] = a.x; r[t][2] = a.y; r[t][3] = a.z; r[t][4] = a.w;
            r[t][5] = b.x; r[t][6] = b.y; r[t][7] = b.z; r[t][8] = b.w;
            r[t][0] = (c0 > 0)       ? row[c0 - 1] : 0.0f;
            r[t][9] = (c0 + 8 < 256) ? row[c0 + 8] : 0.0f;
        }
    }

    float* outbase = y + ((size_t)p << 16) + ((size_t)h0 << 8) + c0;

#pragma unroll
    for (int orow = 0; orow < 4; ++orow) {
        // Column-wise vertical sort over rows orow..orow+2.
        float lo[10], mi[10], hi[10];
#pragma unroll
        for (int j = 0; j < 10; ++j) {
            const float a = r[orow][j], b = r[orow + 1][j], c = r[orow + 2][j];
            lo[j] = min3f(a, b, c);
            mi[j] = med3f(a, b, c);
            hi[j] = max3f(a, b, c);
        }
        float res[8];
#pragma unroll
        for (int k = 0; k < 8; ++k) {
            const float A = max3f(lo[k], lo[k + 1], lo[k + 2]);
            const float B = med3f(mi[k], mi[k + 1], mi[k + 2]);
            const float C = min3f(hi[k], hi[k + 1], hi[k + 2]);
            res[k] = med3f(A, B, C);
        }
        float* out = outbase + (orow << 8);
        *reinterpret_cast<float4*>(out)     = make_float4(res[0], res[1], res[2], res[3]);
        *reinterpret_cast<float4*>(out + 4) = make_float4(res[4], res[5], res[6], res[7]);
    }
}

extern "C" void kernel_launch(void* const* d_in, const int* in_sizes, int n_in,
                              void* d_out, int out_size, void* d_ws, size_t ws_size,
                              hipStream_t stream) {
    const float* x = (const float*)d_in[0];
    float* y = (float*)d_out;
    const int total = out_size / 32;            // 1,048,576 threads (8x4 tiles)
    const int threads = 256;
    const int blocks = (total + threads - 1) / threads;
    median3x3_kernel<<<blocks, threads, 0, stream>>>(x, y, total);
}